// Round 1
// baseline (593.427 us; speedup 1.0000x reference)
//
#include <hip/hip_runtime.h>

// LSTM: HIDDEN=128, SEQ=7, BATCH=65536. fp32 in/out.
//
// R8: structural rewrite — transposed MFMA (A = W_hh tiles streamed from
// global, B = h^T held in registers) with two packing permutations:
//  * M-rows interleave the 4 gates: tile m, row rho=hl*4+g -> j=g*128+m*4+hl.
//    With C-layout row=quad*4+reg, each lane's floatx4 acc = the 4 gates
//    (i,f,g,o) of ONE (batch, hcol=4m+quad) element.
//  * K-dim permuted: k~ = 32*(m>>3) + 8*quad + (m&7), applied to the W_hh
//    packing. h_new produced at (m, quad) then lands at B-frag slot
//    [kk=m>>3][jj=m&7] of lane quad -> h NEVER leaves registers. No LDS h,
//    no inter-wave exchange: each wave owns 32 batch rows independently.
//  * Weights/bias prescaled by log2e (2*log2e for cell gate); cell state
//    stored scaled (c~ = 2*log2e*c) -> all 5 exps are v_exp_f32 with free
//    negate modifier; 2 rcp. ~22 VALU + 7 trans per element.
// One barrier per timestep retained only to keep the block's 4 waves
// phase-aligned for L1 reuse of the weight stream (no data dependency).

#define SEQ 7

typedef _Float16 half8 __attribute__((ext_vector_type(8)));
typedef float floatx4 __attribute__((ext_vector_type(4)));

__device__ __forceinline__ floatx4 mfma16(half8 a, half8 b, floatx4 c) {
  return __builtin_amdgcn_mfma_f32_16x16x32_f16(a, b, c, 0, 0, 0);
}

#define LOG2E 1.4426950408889634f
#define K2 2.885390081777927f  // 2*log2e

// Pack W_hh [512][128] fp32 -> A-fragment-major fp16, gate-interleaved M,
// permuted K, prescaled by log2e (2log2e for cell gate g==2).
// Ap[((m*4+kk)*64 + lane)*8 + jj]:
//   rho = lane&15, quad = lane>>4
//   j = (rho&3)*128 + m*4 + (rho>>2)      (gate g = rho&3, hl = rho>>2)
//   k = 4*(kk*8 + jj) + quad              (inverse of k~ permutation)
__global__ void pack_kernel(const float* __restrict__ Whh,
                            _Float16* __restrict__ Ap) {
  int idx = blockIdx.x * 256 + threadIdx.x;  // 0..65535
  int jj = idx & 7;
  int lane = (idx >> 3) & 63;
  int kk = (idx >> 9) & 3;
  int m = idx >> 11;
  int rho = lane & 15, quad = lane >> 4;
  int g = rho & 3, hl = rho >> 2;
  int j = g * 128 + m * 4 + hl;
  int k = 4 * (kk * 8 + jj) + quad;
  float S = (g == 2) ? K2 : LOG2E;
  Ap[idx] = (_Float16)(S * Whh[j * 128 + k]);
}

__launch_bounds__(256, 2)
__global__ void lstm_kernel(const float* __restrict__ x,
                            const float* __restrict__ x0,
                            const float* __restrict__ Wih,
                            const float* __restrict__ bih,
                            const float* __restrict__ bhh,
                            const float* __restrict__ Wout,
                            const float* __restrict__ boutp,
                            const _Float16* __restrict__ Ap,
                            float* __restrict__ out) {
  // Broadcast tables: per (m, quad) = hcol, the 4 gates' prescaled
  // W_ih and bias (acc init), plus W_out. 4.5 KB, read same-address
  // across 16 lanes -> bank-conflict-free broadcast.
  __shared__ floatx4 Tw[32][4];
  __shared__ floatx4 Tb[32][4];
  __shared__ float Two[32][4];

  const int tid = threadIdx.x;
  for (int i = tid; i < 128; i += 256) {
    int m = i >> 2, q = i & 3;
    int hcol = m * 4 + q;
    floatx4 wv, bv;
#pragma unroll
    for (int g = 0; g < 4; ++g) {
      int j = g * 128 + hcol;
      float S = (g == 2) ? K2 : LOG2E;
      wv[g] = S * Wih[j];
      bv[g] = S * (bih[j] + bhh[j]);
    }
    Tw[m][q] = wv;
    Tb[m][q] = bv;
    Two[m][q] = Wout[hcol];
  }
  __syncthreads();

  const int wv = tid >> 6;
  const int lane = tid & 63;
  const int col = lane & 15;
  const int quad = lane >> 4;
  const int rowbase = blockIdx.x * 128 + wv * 32;
  const float bout = boutp[0];

  const _Float16* ap = Ap + lane * 8;

  // h^T B-fragments, fp16, double set for old/new (h0 = 0).
  half8 bO[2][4], bN[2][4];
#pragma unroll
  for (int bt = 0; bt < 2; ++bt)
#pragma unroll
    for (int kk = 0; kk < 4; ++kk) bO[bt][kk] = (half8)(_Float16)0.0f;

  // Scaled cell state c~ = 2*log2e*c, fp32, static-indexed (stays in regs).
  float cst[2][32];
#pragma unroll
  for (int m = 0; m < 32; ++m) {
    cst[0][m] = 0.0f;
    cst[1][m] = 0.0f;
  }

  const int ll = lane & 31;
  const float* xrow = x + (size_t)(rowbase + ll) * 7;
  float xraw = x0[rowbase + ll];  // t=0 consumes x0
  float* outp = out + (size_t)rowbase * 7;

#pragma unroll 1
  for (int t = 0; t < SEQ; ++t) {
    // prefetch next timestep's input (step t+1 consumes x[:, t])
    float xnext = (t + 1 < SEQ) ? xrow[t] : 0.0f;
    const float xv0 = __shfl(xraw, col, 64);
    const float xv1 = __shfl(xraw, col + 16, 64);
    float pp0 = 0.0f, pp1 = 0.0f;

#pragma unroll
    for (int m = 0; m < 32; ++m) {
      const floatx4 w4 = Tw[m][quad];
      const floatx4 b4 = Tb[m][quad];
      const float wo = Two[m][quad];

      // acc init = x*W_ih + bias (prescaled) -> acc comes out = G*log2e
      floatx4 acc0, acc1;
#pragma unroll
      for (int g = 0; g < 4; ++g) {
        acc0[g] = __builtin_fmaf(w4[g], xv0, b4[g]);
        acc1[g] = __builtin_fmaf(w4[g], xv1, b4[g]);
      }

#pragma unroll
      for (int kk = 0; kk < 4; ++kk) {
        half8 af = *(const half8*)(ap + (m * 4 + kk) * 512);
        acc0 = mfma16(af, bO[0][kk], acc0);
        acc1 = mfma16(af, bO[1][kk], acc1);
      }

      // Fused-reciprocal cell update, exp2 form (free negate modifiers):
      //   A=2^-Gi', B=2^-Gf', C=2^-Gg'', D=2^-Go'   (weights prescaled)
      //   c~' = [c~*(1+A)(1+C) + K2*(1-C)*(1+B)] / [(1+A)(1+B)(1+C)]
      //   E = 2^-c~' ;  h = (1-E) / [(1+D)(1+E)]
      {
        float A = __builtin_amdgcn_exp2f(-acc0[0]);
        float Bv = __builtin_amdgcn_exp2f(-acc0[1]);
        float Cv = __builtin_amdgcn_exp2f(-acc0[2]);
        float Dv = __builtin_amdgcn_exp2f(-acc0[3]);
        float a1 = 1.0f + A, b1 = 1.0f + Bv, c1 = 1.0f + Cv;
        float ac = a1 * c1;
        float t1 = __builtin_fmaf(Cv, -K2, K2);  // K2*(1-C)
        float num = __builtin_fmaf(cst[0][m], ac, t1 * b1);
        float cn = num * __builtin_amdgcn_rcpf(ac * b1);
        cst[0][m] = cn;
        float E = __builtin_amdgcn_exp2f(-cn);
        float hn = (1.0f - E) *
                   __builtin_amdgcn_rcpf((1.0f + Dv) * (1.0f + E));
        pp0 = __builtin_fmaf(hn, wo, pp0);
        bN[0][m >> 3][m & 7] = (_Float16)hn;  // lands in next B-frag slot
      }
      {
        float A = __builtin_amdgcn_exp2f(-acc1[0]);
        float Bv = __builtin_amdgcn_exp2f(-acc1[1]);
        float Cv = __builtin_amdgcn_exp2f(-acc1[2]);
        float Dv = __builtin_amdgcn_exp2f(-acc1[3]);
        float a1 = 1.0f + A, b1 = 1.0f + Bv, c1 = 1.0f + Cv;
        float ac = a1 * c1;
        float t1 = __builtin_fmaf(Cv, -K2, K2);
        float num = __builtin_fmaf(cst[1][m], ac, t1 * b1);
        float cn = num * __builtin_amdgcn_rcpf(ac * b1);
        cst[1][m] = cn;
        float E = __builtin_amdgcn_exp2f(-cn);
        float hn = (1.0f - E) *
                   __builtin_amdgcn_rcpf((1.0f + Dv) * (1.0f + E));
        pp1 = __builtin_fmaf(hn, wo, pp1);
        bN[1][m >> 3][m & 7] = (_Float16)hn;
      }
    }

    // pred: sum the 4 quads' partial dot-products (each lane covered
    // hcols {4m+quad}), then lanes 0..15 store batch bt*16+col.
    float v0 = pp0;
    v0 += __shfl_xor(v0, 16, 64);
    v0 += __shfl_xor(v0, 32, 64);
    float v1 = pp1;
    v1 += __shfl_xor(v1, 16, 64);
    v1 += __shfl_xor(v1, 32, 64);
    if (lane < 16) {
      outp[lane * 7 + t] = v0 + bout;
      outp[(16 + lane) * 7 + t] = v1 + bout;
    }

    // rotate h fragments; no LDS, no data-dependent barrier needed.
#pragma unroll
    for (int bt = 0; bt < 2; ++bt)
#pragma unroll
      for (int kk = 0; kk < 4; ++kk) bO[bt][kk] = bN[bt][kk];
    xraw = xnext;

    // keep the block's 4 (independent) waves phase-aligned so they share
    // the streamed W_hh fragments in L1. Work is symmetric -> cheap.
    __syncthreads();
  }
}

extern "C" void kernel_launch(void* const* d_in, const int* in_sizes, int n_in,
                              void* d_out, int out_size, void* d_ws,
                              size_t ws_size, hipStream_t stream) {
  const float* x = (const float*)d_in[0];
  const float* x0 = (const float*)d_in[1];
  const float* Wih = (const float*)d_in[2];
  const float* Whh = (const float*)d_in[3];
  const float* bih = (const float*)d_in[4];
  const float* bhh = (const float*)d_in[5];
  const float* Wout = (const float*)d_in[6];
  const float* bout = (const float*)d_in[7];
  float* out = (float*)d_out;
  _Float16* Ap = (_Float16*)d_ws;  // 128 KB packed/prescaled W_hh

  pack_kernel<<<256, 256, 0, stream>>>(Whh, Ap);
  lstm_kernel<<<65536 / 128, 256, 0, stream>>>(x, x0, Wih, bih, bhh, Wout,
                                               bout, Ap, out);
}

// Round 2
// 201.794 us; speedup vs baseline: 2.9408x; 2.9408x over previous
//
#include <hip/hip_runtime.h>

// LSTM: HIDDEN=128, SEQ=7, BATCH=65536. fp32 in/out.
//
// R9: weight-stationary rewrite. R8 post-mortem: h-in-registers spilled
// (FETCH 827MB + WRITE 248MB of scratch) and full-weight-per-wave streaming
// is a 93us/CU VMEM floor. Fix: weights (t-invariant) live in registers --
// 8 waves x 16-hcol slices, 16KB = 64 VGPR/lane loaded ONCE for all 7
// timesteps. h exchanged via LDS (R7-proven 272B-stride layout, dbuf,
// 1 barrier/t). BT=64 per 512-thread block.
//  * N-pack gate-interleaved: j = g*128 + 16w + col -> each lane's floatx4
//    acc = 4 gates (i,f,g,o) of ONE (batch row, hcol) element.
//  * bias + x*W_ih folded into MFMA C-init (prescaled by log2e / 2log2e).
//  * exp2-form fused-reciprocal cell math (R8-verified numerics):
//    5 exp2 (free negate) + 2 rcp per element.
//  * per-mt {ds_read A, 16 MFMA, epilogue} interleave for pipe mixing.

#define SEQ 7

typedef _Float16 half8 __attribute__((ext_vector_type(8)));
typedef float floatx4 __attribute__((ext_vector_type(4)));

__device__ __forceinline__ floatx4 mfma16(half8 a, half8 b, floatx4 c) {
  return __builtin_amdgcn_mfma_f32_16x16x32_f16(a, b, c, 0, 0, 0);
}

#define LOG2E 1.4426950408889634f
#define K2 2.885390081777927f  // 2*log2e

// Pack W_hh [512][128] fp32 -> B-fragment-major fp16, prescaled.
// Bp[((nt*4+kk)*64 + lane)*8 + jj] = S(g) * Whh[j][k]
//   nt = g*8 + w (wave w owns hcols [16w,16w+16)), col = lane&15,
//   quad = lane>>4, j = g*128 + w*16 + col, k = 32*kk + 8*quad + jj.
// B-layout (R7-proven): lane kq*16+col holds B[k=kq*8+jj][n=col] per K-step.
__global__ void pack_kernel(const float* __restrict__ Whh,
                            _Float16* __restrict__ Bp) {
  int idx = blockIdx.x * 256 + threadIdx.x;  // 0..65535
  int jj = idx & 7;
  int lane = (idx >> 3) & 63;
  int kk = (idx >> 9) & 3;
  int nt = idx >> 11;  // 0..31
  int g = nt >> 3, w = nt & 7;
  int col = lane & 15, quad = lane >> 4;
  int j = g * 128 + w * 16 + col;
  int k = 32 * kk + 8 * quad + jj;
  float S = (g == 2) ? K2 : LOG2E;
  Bp[idx] = (_Float16)(S * Whh[j * 128 + k]);
}

__launch_bounds__(512, 2)
__global__ void lstm_kernel(const float* __restrict__ x,
                            const float* __restrict__ x0,
                            const float* __restrict__ Wih,
                            const float* __restrict__ bih,
                            const float* __restrict__ bhh,
                            const float* __restrict__ Wout,
                            const float* __restrict__ boutp,
                            const _Float16* __restrict__ Bp,
                            float* __restrict__ out) {
  // h staged fp16, double-buffered, 272B row stride (R7-proven pad: +8).
  __shared__ _Float16 Ah[2][64][136];
  __shared__ float xs[2][64];
  __shared__ float predp[2][8][64];

  const int tid = threadIdx.x;
  const int w = tid >> 6;  // wave 0..7: owns hcols [16w, 16w+16)
  const int lane = tid & 63;
  const int col = lane & 15;
  const int quad = lane >> 4;
  const int rowbase = blockIdx.x * 64;

  // Weight fragments: 16 KB/wave held in registers for all timesteps.
  half8 bw[4][4];
#pragma unroll
  for (int g = 0; g < 4; ++g)
#pragma unroll
    for (int kk = 0; kk < 4; ++kk)
      bw[g][kk] =
          *(const half8*)(Bp + (((g * 8 + w) * 4 + kk) * 64 + lane) * 8);

  // Per-lane epilogue constants for gate-col j = g*128 + 16w + col.
  float wih_r[4], bias_r[4];
#pragma unroll
  for (int g = 0; g < 4; ++g) {
    int j = g * 128 + w * 16 + col;
    float S = (g == 2) ? K2 : LOG2E;
    wih_r[g] = S * Wih[j];
    bias_r[g] = S * (bih[j] + bhh[j]);
  }
  const float wout_r = Wout[w * 16 + col];
  const float bout = boutp[0];

  // Scaled cell state c~ = 2log2e*c. Static-indexed -> registers.
  float c_r[4][4];
#pragma unroll
  for (int mt = 0; mt < 4; ++mt)
#pragma unroll
    for (int r = 0; r < 4; ++r) c_r[mt][r] = 0.f;

  if (tid < 64) xs[0][tid] = x0[rowbase + tid];  // t=0 consumes x0
  __syncthreads();

#pragma unroll 1
  for (int t = 0; t < SEQ; ++t) {
    const int cur = t & 1, nxt = cur ^ 1;

    // drain pred of t-1 (predp[cur] complete as of last barrier)
    if (t > 0 && tid < 64) {
      float p = bout;
#pragma unroll
      for (int ww = 0; ww < 8; ++ww) p += predp[cur][ww][tid];
      out[(size_t)(rowbase + tid) * 7 + (t - 1)] = p;
    }
    // prefetch input for t+1 (consumes x[:, t])
    if (t + 1 < SEQ && tid < 64) {
      xs[nxt][tid] = x[(size_t)(rowbase + tid) * 7 + t];
    }

#pragma unroll
    for (int mt = 0; mt < 4; ++mt) {
      // x for the 4 rows (mt*16 + quad*4 + r) this lane covers; broadcast.
      floatx4 xq = *(const floatx4*)&xs[cur][mt * 16 + quad * 4];

      // acc init = x*W_ih + bias (prescaled) -> MFMA C operand.
      floatx4 acc[4];
#pragma unroll
      for (int g = 0; g < 4; ++g)
#pragma unroll
        for (int r = 0; r < 4; ++r)
          acc[g][r] = __builtin_fmaf(wih_r[g], xq[r], bias_r[g]);

      if (t != 0) {  // h(0)=0: skip GEMM at t=0 (uniform branch)
        half8 ah[4];
#pragma unroll
        for (int kk = 0; kk < 4; ++kk)
          ah[kk] =
              *(const half8*)&Ah[cur][mt * 16 + col][kk * 32 + quad * 8];
#pragma unroll
        for (int g = 0; g < 4; ++g)
#pragma unroll
          for (int kk = 0; kk < 4; ++kk)
            acc[g] = mfma16(ah[kk], bw[g][kk], acc[g]);
      }

      // Fused-reciprocal cell update (R8-verified numerics), per element:
      //   A=2^-Gi', B=2^-Gf', C=2^-Gg'', D=2^-Go'
      //   c~' = [c~(1+A)(1+C) + K2(1-C)(1+B)] / [(1+A)(1+B)(1+C)]
      //   E = 2^-c~' ; h = (1-E) / [(1+D)(1+E)]
      float pp[4];
#pragma unroll
      for (int r = 0; r < 4; ++r) {
        float A = __builtin_amdgcn_exp2f(-acc[0][r]);
        float Bv = __builtin_amdgcn_exp2f(-acc[1][r]);
        float Cv = __builtin_amdgcn_exp2f(-acc[2][r]);
        float Dv = __builtin_amdgcn_exp2f(-acc[3][r]);
        float a1 = 1.0f + A, b1 = 1.0f + Bv, c1 = 1.0f + Cv;
        float ac = a1 * c1;
        float t1 = __builtin_fmaf(Cv, -K2, K2);  // K2*(1-C)
        float num = __builtin_fmaf(c_r[mt][r], ac, t1 * b1);
        float cn = num * __builtin_amdgcn_rcpf(ac * b1);
        c_r[mt][r] = cn;
        float E = __builtin_amdgcn_exp2f(-cn);
        float hn =
            (1.0f - E) * __builtin_amdgcn_rcpf((1.0f + Dv) * (1.0f + E));
        pp[r] = hn * wout_r;
        // stage h_new (fp16) into next buffer; lane owns hcol 16w+col
        Ah[nxt][mt * 16 + quad * 4 + r][w * 16 + col] = (_Float16)hn;
      }
      // pred partial: reduce over this wave's 16 hcols (col lanes)
#pragma unroll
      for (int r = 0; r < 4; ++r) {
        float v = pp[r];
        v += __shfl_xor(v, 1, 64);
        v += __shfl_xor(v, 2, 64);
        v += __shfl_xor(v, 4, 64);
        v += __shfl_xor(v, 8, 64);
        if (col == 0) predp[nxt][w][mt * 16 + quad * 4 + r] = v;
      }
    }
    // single barrier: h staging, predp, xs prefetch complete
    __syncthreads();
  }

  // drain pred of t=6 (written to predp[SEQ&1])
  if (tid < 64) {
    float p = bout;
#pragma unroll
    for (int ww = 0; ww < 8; ++ww) p += predp[SEQ & 1][ww][tid];
    out[(size_t)(rowbase + tid) * 7 + (SEQ - 1)] = p;
  }
}

extern "C" void kernel_launch(void* const* d_in, const int* in_sizes, int n_in,
                              void* d_out, int out_size, void* d_ws,
                              size_t ws_size, hipStream_t stream) {
  const float* x = (const float*)d_in[0];
  const float* x0 = (const float*)d_in[1];
  const float* Wih = (const float*)d_in[2];
  const float* Whh = (const float*)d_in[3];
  const float* bih = (const float*)d_in[4];
  const float* bhh = (const float*)d_in[5];
  const float* Wout = (const float*)d_in[6];
  const float* bout = (const float*)d_in[7];
  float* out = (float*)d_out;
  _Float16* Bp = (_Float16*)d_ws;  // 128 KB packed/prescaled W_hh

  pack_kernel<<<256, 256, 0, stream>>>(Whh, Bp);
  lstm_kernel<<<65536 / 64, 512, 0, stream>>>(x, x0, Wih, bih, bhh, Wout,
                                              bout, Bp, out);
}

// Round 3
// 187.172 us; speedup vs baseline: 3.1705x; 1.0781x over previous
//
#include <hip/hip_runtime.h>

// LSTM: HIDDEN=128, SEQ=7, BATCH=65536. fp32 in/out.
//
// R10: R9 weight-stationary structure +
//  (a) MFMA-pred: pred(t)=h(t)·W_out computed as a GEMM side-column during
//      step t+1 (and a tail step for t=6), using the SAME A-fragments the
//      gate GEMM reads. W_out packed as fp16 hi+lo B-fragments (col 0 of a
//      16-col tile; other cols zero). Wave w preds its own mt==w row tile
//      -> perfectly balanced, removes ALL shfl-reduces + predp LDS (+~35%
//      of VALU issue) for +8 MFMA/wave/t on a 14%-utilized pipe.
//  (b) BT=128 per 512-thread block, grid=512: 2 blocks/CU, 141KB LDS,
//      whole problem resident in ONE generation; 2x work per barrier
//      interval for latency hiding. __launch_bounds__(512,4) caps VGPR=128.
// Epilogue numerics unchanged (R8/R9-verified exp2-form fused-reciprocal).

#define SEQ 7
#define BT 128

typedef _Float16 half8 __attribute__((ext_vector_type(8)));
typedef float floatx4 __attribute__((ext_vector_type(4)));

__device__ __forceinline__ floatx4 mfma16(half8 a, half8 b, floatx4 c) {
  return __builtin_amdgcn_mfma_f32_16x16x32_f16(a, b, c, 0, 0, 0);
}

#define LOG2E 1.4426950408889634f
#define K2 2.885390081777927f  // 2*log2e

// Pack W_hh [512][128] fp32 -> B-fragment-major fp16, prescaled (idx<65536):
//   Bp[((nt*4+kk)*64 + lane)*8 + jj] = S(g) * Whh[j][k]
//   nt=g*8+w, j=g*128+w*16+col, k=32kk+8quad+jj (B-layout: lane kq*16+col
//   holds B[k=kq*8+jj][n=col] -- R7-proven).
// idx in [65536, 69632): W_out hi/lo fragments, col-0-only 16-col tile:
//   Bp[65536 + hl*2048 + (kk*64+lane)*8 + jj] =
//     col==0 ? (hl ? lo : hi) of Wout[32kk+8quad+jj] : 0
__global__ void pack_kernel(const float* __restrict__ Whh,
                            const float* __restrict__ Wout,
                            _Float16* __restrict__ Bp) {
  int idx = blockIdx.x * 256 + threadIdx.x;  // 0..69631
  if (idx < 65536) {
    int jj = idx & 7;
    int lane = (idx >> 3) & 63;
    int kk = (idx >> 9) & 3;
    int nt = idx >> 11;  // 0..31
    int g = nt >> 3, w = nt & 7;
    int col = lane & 15, quad = lane >> 4;
    int j = g * 128 + w * 16 + col;
    int k = 32 * kk + 8 * quad + jj;
    float S = (g == 2) ? K2 : LOG2E;
    Bp[idx] = (_Float16)(S * Whh[j * 128 + k]);
  } else {
    int pos = idx - 65536;  // 0..4095
    int hl = pos >> 11;     // 0 = hi, 1 = lo
    int e = pos & 2047;
    int jj = e & 7;
    int lane = (e >> 3) & 63;
    int kk = e >> 9;
    int col = lane & 15, quad = lane >> 4;
    int k = 32 * kk + 8 * quad + jj;
    float wv = Wout[k];
    _Float16 hi = (_Float16)wv;
    _Float16 v = hl ? (_Float16)(wv - (float)hi) : hi;
    Bp[idx] = (col == 0) ? v : (_Float16)0.0f;
  }
}

__launch_bounds__(512, 4)
__global__ void lstm_kernel(const float* __restrict__ x,
                            const float* __restrict__ x0,
                            const float* __restrict__ Wih,
                            const float* __restrict__ bih,
                            const float* __restrict__ bhh,
                            const float* __restrict__ boutp,
                            const _Float16* __restrict__ Bp,
                            float* __restrict__ out) {
  // h staged fp16, double-buffered, 272B row stride (+8 pad, R7-proven).
  __shared__ _Float16 Ah[2][BT][136];  // 69,632 B
  __shared__ float xs[2][BT];          // 1 KB

  const int tid = threadIdx.x;
  const int w = tid >> 6;  // wave 0..7: owns hcols [16w,16w+16)
  const int lane = tid & 63;
  const int col = lane & 15;
  const int quad = lane >> 4;
  const int rowbase = blockIdx.x * BT;

  // Weight fragments (registers, loaded once for all 7 timesteps).
  half8 bw[4][4];  // gate GEMM B-frags: 32 VGPR
#pragma unroll
  for (int g = 0; g < 4; ++g)
#pragma unroll
    for (int kk = 0; kk < 4; ++kk)
      bw[g][kk] =
          *(const half8*)(Bp + (((g * 8 + w) * 4 + kk) * 64 + lane) * 8);
  half8 bwo[2][4];  // W_out hi/lo pred B-frags: 16 VGPR
#pragma unroll
  for (int hl = 0; hl < 2; ++hl)
#pragma unroll
    for (int kk = 0; kk < 4; ++kk)
      bwo[hl][kk] =
          *(const half8*)(Bp + 65536 + hl * 2048 + (kk * 64 + lane) * 8);

  // Per-lane epilogue constants, gate-col j = g*128 + 16w + col.
  float wih_r[4], bias_r[4];
#pragma unroll
  for (int g = 0; g < 4; ++g) {
    int j = g * 128 + w * 16 + col;
    float S = (g == 2) ? K2 : LOG2E;
    wih_r[g] = S * Wih[j];
    bias_r[g] = S * (bih[j] + bhh[j]);
  }
  const float bout = boutp[0];

  // Scaled cell state c~ = 2log2e*c, static-indexed -> registers.
  float c_r[8][4];
#pragma unroll
  for (int mt = 0; mt < 8; ++mt)
#pragma unroll
    for (int r = 0; r < 4; ++r) c_r[mt][r] = 0.f;

  if (tid < BT) xs[0][tid] = x0[rowbase + tid];  // t=0 consumes x0
  __syncthreads();

#pragma unroll 1
  for (int t = 0; t < SEQ; ++t) {
    const int cur = t & 1, nxt = cur ^ 1;

    // prefetch input for t+1 (consumes x[:, t])
    if (t + 1 < SEQ && tid < BT) {
      xs[nxt][tid] = x[(size_t)(rowbase + tid) * 7 + t];
    }

#pragma unroll
    for (int mt = 0; mt < 8; ++mt) {
      // x for the 4 rows (mt*16 + quad*4 + r) this lane covers.
      floatx4 xq = *(const floatx4*)&xs[cur][mt * 16 + quad * 4];

      // acc init = x*W_ih + bias (prescaled) -> MFMA C operand.
      floatx4 acc[4];
#pragma unroll
      for (int g = 0; g < 4; ++g)
#pragma unroll
        for (int r = 0; r < 4; ++r)
          acc[g][r] = __builtin_fmaf(wih_r[g], xq[r], bias_r[g]);

      if (t != 0) {  // h(0)=0: skip GEMM at t=0
        floatx4 ap = (floatx4){0.f, 0.f, 0.f, 0.f};  // pred(t-1) partial
#pragma unroll
        for (int kk = 0; kk < 4; ++kk) {
          half8 ah =
              *(const half8*)&Ah[cur][mt * 16 + col][kk * 32 + quad * 8];
#pragma unroll
          for (int g = 0; g < 4; ++g) acc[g] = mfma16(ah, bw[g][kk], acc[g]);
          if (mt == w) {  // wave w preds its own row tile (full K in ah)
            ap = mfma16(ah, bwo[0][kk], ap);
            ap = mfma16(ah, bwo[1][kk], ap);
          }
        }
        if (mt == w && col == 0) {
#pragma unroll
          for (int r = 0; r < 4; ++r)
            out[(size_t)(rowbase + w * 16 + quad * 4 + r) * 7 + (t - 1)] =
                ap[r] + bout;
        }
      }

      // Fused-reciprocal cell update (exp2 form, prescaled weights):
      //   A=2^-Gi', B=2^-Gf', C=2^-Gg'', D=2^-Go'
      //   c~' = [c~(1+A)(1+C) + K2(1-C)(1+B)] / [(1+A)(1+B)(1+C)]
      //   E = 2^-c~' ; h = (1-E)/[(1+D)(1+E)]
#pragma unroll
      for (int r = 0; r < 4; ++r) {
        float A = __builtin_amdgcn_exp2f(-acc[0][r]);
        float Bv = __builtin_amdgcn_exp2f(-acc[1][r]);
        float Cv = __builtin_amdgcn_exp2f(-acc[2][r]);
        float Dv = __builtin_amdgcn_exp2f(-acc[3][r]);
        float a1 = 1.0f + A, b1 = 1.0f + Bv, c1 = 1.0f + Cv;
        float ac = a1 * c1;
        float t1 = __builtin_fmaf(Cv, -K2, K2);  // K2*(1-C)
        float num = __builtin_fmaf(c_r[mt][r], ac, t1 * b1);
        float cn = num * __builtin_amdgcn_rcpf(ac * b1);
        c_r[mt][r] = cn;
        float E = __builtin_amdgcn_exp2f(-cn);
        float hn =
            (1.0f - E) * __builtin_amdgcn_rcpf((1.0f + Dv) * (1.0f + E));
        // stage h_new (fp16); lane owns hcol 16w+col
        Ah[nxt][mt * 16 + quad * 4 + r][w * 16 + col] = (_Float16)hn;
      }
    }
    // single barrier per t: h staging + xs prefetch complete
    __syncthreads();
  }

  // tail: pred(6) from h(6) staged in Ah[SEQ&1] (= Ah[1])
  {
    floatx4 ap = (floatx4){0.f, 0.f, 0.f, 0.f};
#pragma unroll
    for (int kk = 0; kk < 4; ++kk) {
      half8 ah = *(const half8*)&Ah[1][w * 16 + col][kk * 32 + quad * 8];
      ap = mfma16(ah, bwo[0][kk], ap);
      ap = mfma16(ah, bwo[1][kk], ap);
    }
    if (col == 0) {
#pragma unroll
      for (int r = 0; r < 4; ++r)
        out[(size_t)(rowbase + w * 16 + quad * 4 + r) * 7 + 6] = ap[r] + bout;
    }
  }
}

extern "C" void kernel_launch(void* const* d_in, const int* in_sizes, int n_in,
                              void* d_out, int out_size, void* d_ws,
                              size_t ws_size, hipStream_t stream) {
  const float* x = (const float*)d_in[0];
  const float* x0 = (const float*)d_in[1];
  const float* Wih = (const float*)d_in[2];
  const float* Whh = (const float*)d_in[3];
  const float* bih = (const float*)d_in[4];
  const float* bhh = (const float*)d_in[5];
  const float* Wout = (const float*)d_in[6];
  const float* bout = (const float*)d_in[7];
  float* out = (float*)d_out;
  _Float16* Bp = (_Float16*)d_ws;  // 136 KB packed weights + wout frags

  pack_kernel<<<272, 256, 0, stream>>>(Whh, Wout, Bp);
  lstm_kernel<<<65536 / BT, 512, 0, stream>>>(x, x0, Wih, bih, bhh, bout, Bp,
                                              out);
}

// Round 4
// 163.345 us; speedup vs baseline: 3.6330x; 1.1459x over previous
//
#include <hip/hip_runtime.h>

// LSTM: HIDDEN=128, SEQ=7, BATCH=65536. fp32 in/out.
//
// R11: R10 dataflow (weight-stationary regs, MFMA-pred side column, bias
// folded into MFMA C-init, exp2 fused-reciprocal cell math, 1 barrier/t)
// with the register budget actually fitting the 16-wave/CU tier:
//  * R10 post-mortem: (512,4) cap=128 vs demand ~135 -> 400 MB scratch
//    spill traffic (FETCH 188 MB / WRITE 203 MB) = the whole 127 us.
//  * Fix 1: W_out hi/lo fragments move to LDS (-16 VGPR); read once per
//    wave per t (canonical conflict-free ds_read_b128 pattern).
//  * Fix 2: 1024-thread blocks, BT=128, 16 waves: wave (ct,half) owns
//    row-tiles [4*half,4*half+4) x hcols [16ct,16ct+16) -> c_r[4][4]
//    (-16 VGPR), mt-unroll halved. Demand ~100 vs cap 128.
//  * Pred: wave (ct<4, half) preds row-tile 4*half+ct (hi+lo, 8 MFMA),
//    exactly one wave per tile, stores direct from C-fragment.

#define SEQ 7
#define BT 128

typedef _Float16 half8 __attribute__((ext_vector_type(8)));
typedef float floatx4 __attribute__((ext_vector_type(4)));

__device__ __forceinline__ floatx4 mfma16(half8 a, half8 b, floatx4 c) {
  return __builtin_amdgcn_mfma_f32_16x16x32_f16(a, b, c, 0, 0, 0);
}

#define LOG2E 1.4426950408889634f
#define K2 2.885390081777927f  // 2*log2e

// Pack W_hh [512][128] fp32 -> B-fragment-major fp16, prescaled (idx<65536):
//   Bp[((nt*4+kk)*64 + lane)*8 + jj] = S(g) * Whh[j][k]
//   nt=g*8+ct, j=g*128+ct*16+col, k=32kk+8quad+jj (B-layout: lane kq*16+col
//   holds B[k=kq*8+jj][n=col] -- R7-proven).
// idx in [65536, 69632): W_out hi/lo fragments, col-0-only 16-col tile.
__global__ void pack_kernel(const float* __restrict__ Whh,
                            const float* __restrict__ Wout,
                            _Float16* __restrict__ Bp) {
  int idx = blockIdx.x * 256 + threadIdx.x;  // 0..69631
  if (idx < 65536) {
    int jj = idx & 7;
    int lane = (idx >> 3) & 63;
    int kk = (idx >> 9) & 3;
    int nt = idx >> 11;  // 0..31
    int g = nt >> 3, ct = nt & 7;
    int col = lane & 15, quad = lane >> 4;
    int j = g * 128 + ct * 16 + col;
    int k = 32 * kk + 8 * quad + jj;
    float S = (g == 2) ? K2 : LOG2E;
    Bp[idx] = (_Float16)(S * Whh[j * 128 + k]);
  } else {
    int pos = idx - 65536;  // 0..4095
    int hl = pos >> 11;     // 0 = hi, 1 = lo
    int e = pos & 2047;
    int jj = e & 7;
    int lane = (e >> 3) & 63;
    int kk = e >> 9;
    int col = lane & 15, quad = lane >> 4;
    int k = 32 * kk + 8 * quad + jj;
    float wv = Wout[k];
    _Float16 hi = (_Float16)wv;
    _Float16 v = hl ? (_Float16)(wv - (float)hi) : hi;
    Bp[idx] = (col == 0) ? v : (_Float16)0.0f;
  }
}

__launch_bounds__(1024, 4)
__global__ void lstm_kernel(const float* __restrict__ x,
                            const float* __restrict__ x0,
                            const float* __restrict__ Wih,
                            const float* __restrict__ bih,
                            const float* __restrict__ bhh,
                            const float* __restrict__ boutp,
                            const _Float16* __restrict__ Bp,
                            float* __restrict__ out) {
  // h staged fp16, double-buffered, 272B row stride (+8 pad: 2-way-free
  // ds_read_b128, ~4-way ds_write_b16 -- known ~5us, accepted).
  __shared__ _Float16 Ah[2][BT][136];  // 69,632 B
  __shared__ float xs[2][BT];          // 1 KB
  __shared__ _Float16 Wo[4096];        // 8 KB W_out hi/lo B-fragments

  const int tid = threadIdx.x;
  const int wv = tid >> 6;   // 0..15
  const int lane = tid & 63;
  const int col = lane & 15;
  const int quad = lane >> 4;
  const int ct = wv & 7;        // col-tile: hcols [16ct, 16ct+16)
  const int half = wv >> 3;     // row half: mt in [4*half, 4*half+4)
  const int mtbase = 4 * half;
  const int rowbase = blockIdx.x * BT;

  // stage W_out fragments into LDS (512 x 16B)
  if (tid < 512) ((half8*)Wo)[tid] = ((const half8*)(Bp + 65536))[tid];

  // Gate-GEMM weight fragments: registers, loaded once for all timesteps.
  half8 bw[4][4];  // 32 VGPR
#pragma unroll
  for (int g = 0; g < 4; ++g)
#pragma unroll
    for (int kk = 0; kk < 4; ++kk)
      bw[g][kk] =
          *(const half8*)(Bp + (((g * 8 + ct) * 4 + kk) * 64 + lane) * 8);

  // Per-lane epilogue constants, gate-col j = g*128 + 16ct + col.
  float wih_r[4], bias_r[4];
#pragma unroll
  for (int g = 0; g < 4; ++g) {
    int j = g * 128 + ct * 16 + col;
    float S = (g == 2) ? K2 : LOG2E;
    wih_r[g] = S * Wih[j];
    bias_r[g] = S * (bih[j] + bhh[j]);
  }
  const float bout = boutp[0];

  // Scaled cell state c~ = 2log2e*c, static-indexed -> registers.
  float c_r[4][4];
#pragma unroll
  for (int mi = 0; mi < 4; ++mi)
#pragma unroll
    for (int r = 0; r < 4; ++r) c_r[mi][r] = 0.f;

  if (tid < BT) xs[0][tid] = x0[rowbase + tid];  // t=0 consumes x0
  __syncthreads();

#pragma unroll 1
  for (int t = 0; t < SEQ; ++t) {
    const int cur = t & 1, nxt = cur ^ 1;

    // prefetch input for t+1 (consumes x[:, t])
    if (t + 1 < SEQ && tid < BT) {
      xs[nxt][tid] = x[(size_t)(rowbase + tid) * 7 + t];
    }

#pragma unroll
    for (int mi = 0; mi < 4; ++mi) {
      const int mt = mtbase + mi;
      // x for the 4 rows (mt*16 + quad*4 + r) this lane covers.
      floatx4 xq = *(const floatx4*)&xs[cur][mt * 16 + quad * 4];

      // acc init = x*W_ih + bias (prescaled) -> MFMA C operand.
      floatx4 acc[4];
#pragma unroll
      for (int g = 0; g < 4; ++g)
#pragma unroll
        for (int r = 0; r < 4; ++r)
          acc[g][r] = __builtin_fmaf(wih_r[g], xq[r], bias_r[g]);

      const bool dopred = (mi == (ct & 3)) && (ct < 4);  // wave-uniform

      if (t != 0) {  // h(0)=0: skip GEMM at t=0
        floatx4 ap = (floatx4){0.f, 0.f, 0.f, 0.f};  // pred(t-1) partial
#pragma unroll
        for (int kk = 0; kk < 4; ++kk) {
          half8 ah =
              *(const half8*)&Ah[cur][mt * 16 + col][kk * 32 + quad * 8];
#pragma unroll
          for (int g = 0; g < 4; ++g) acc[g] = mfma16(ah, bw[g][kk], acc[g]);
          if (dopred) {  // this wave preds its own row tile (full K in ah)
            half8 bo0 = *(const half8*)&Wo[(kk * 64 + lane) * 8];
            half8 bo1 = *(const half8*)&Wo[2048 + (kk * 64 + lane) * 8];
            ap = mfma16(ah, bo0, ap);
            ap = mfma16(ah, bo1, ap);
          }
        }
        if (dopred && col == 0) {
#pragma unroll
          for (int r = 0; r < 4; ++r)
            out[(size_t)(rowbase + mt * 16 + quad * 4 + r) * 7 + (t - 1)] =
                ap[r] + bout;
        }
      }

      // Fused-reciprocal cell update (exp2 form, prescaled weights):
      //   A=2^-Gi', B=2^-Gf', C=2^-Gg'', D=2^-Go'
      //   c~' = [c~(1+A)(1+C) + K2(1-C)(1+B)] / [(1+A)(1+B)(1+C)]
      //   E = 2^-c~' ; h = (1-E)/[(1+D)(1+E)]
#pragma unroll
      for (int r = 0; r < 4; ++r) {
        float A = __builtin_amdgcn_exp2f(-acc[0][r]);
        float Bv = __builtin_amdgcn_exp2f(-acc[1][r]);
        float Cv = __builtin_amdgcn_exp2f(-acc[2][r]);
        float Dv = __builtin_amdgcn_exp2f(-acc[3][r]);
        float a1 = 1.0f + A, b1 = 1.0f + Bv, c1 = 1.0f + Cv;
        float ac = a1 * c1;
        float t1 = __builtin_fmaf(Cv, -K2, K2);  // K2*(1-C)
        float num = __builtin_fmaf(c_r[mi][r], ac, t1 * b1);
        float cn = num * __builtin_amdgcn_rcpf(ac * b1);
        c_r[mi][r] = cn;
        float E = __builtin_amdgcn_exp2f(-cn);
        float hn =
            (1.0f - E) * __builtin_amdgcn_rcpf((1.0f + Dv) * (1.0f + E));
        // stage h_new (fp16); lane owns hcol 16ct+col
        Ah[nxt][mt * 16 + quad * 4 + r][ct * 16 + col] = (_Float16)hn;
      }
    }
    // single barrier per t: h staging + xs prefetch complete
    __syncthreads();
  }

  // tail: pred(6) from h(6) staged in Ah[1]
  if (ct < 4) {
    const int mt = mtbase + (ct & 3);
    floatx4 ap = (floatx4){0.f, 0.f, 0.f, 0.f};
#pragma unroll
    for (int kk = 0; kk < 4; ++kk) {
      half8 ah = *(const half8*)&Ah[1][mt * 16 + col][kk * 32 + quad * 8];
      half8 bo0 = *(const half8*)&Wo[(kk * 64 + lane) * 8];
      half8 bo1 = *(const half8*)&Wo[2048 + (kk * 64 + lane) * 8];
      ap = mfma16(ah, bo0, ap);
      ap = mfma16(ah, bo1, ap);
    }
    if (col == 0) {
#pragma unroll
      for (int r = 0; r < 4; ++r)
        out[(size_t)(rowbase + mt * 16 + quad * 4 + r) * 7 + 6] =
            ap[r] + bout;
    }
  }
}

extern "C" void kernel_launch(void* const* d_in, const int* in_sizes, int n_in,
                              void* d_out, int out_size, void* d_ws,
                              size_t ws_size, hipStream_t stream) {
  const float* x = (const float*)d_in[0];
  const float* x0 = (const float*)d_in[1];
  const float* Wih = (const float*)d_in[2];
  const float* Whh = (const float*)d_in[3];
  const float* bih = (const float*)d_in[4];
  const float* bhh = (const float*)d_in[5];
  const float* Wout = (const float*)d_in[6];
  const float* bout = (const float*)d_in[7];
  float* out = (float*)d_out;
  _Float16* Bp = (_Float16*)d_ws;  // 136 KB packed weights + wout frags

  pack_kernel<<<272, 256, 0, stream>>>(Whh, Wout, Bp);
  lstm_kernel<<<65536 / BT, 1024, 0, stream>>>(x, x0, Wih, bih, bhh, bout,
                                               Bp, out);
}

// Round 5
// 158.042 us; speedup vs baseline: 3.7549x; 1.0336x over previous
//
#include <hip/hip_runtime.h>

// LSTM: HIDDEN=128, SEQ=7, BATCH=65536. fp32 in/out.
//
// R12: R11 dataflow at the spill-free operating point.
//  * R10/R11 post-mortem: __launch_bounds__ 2nd arg behaves as min
//    BLOCKS/CU here (CUDA semantics): (512,4)/(1024,4) => 32 waves/CU
//    => 64-reg cap => spills (WRITE 400MB / 54.8MB). R9's (512,2)
//    measured 76 VGPR, zero spill. Also: half8 = 4 VGPRs, so bw[4][4]
//    is 64 regs (not 32) -- demand ~110 can never fit a 64 cap.
//  * Fix: 512-thread blocks, BT=64, (512,2) -- 128-reg cap under either
//    interpretation of the 2nd arg; demand fits. LDS 43.5KB => 2
//    blocks/CU => 16 waves/CU.
//  * Unchanged: weight-stationary B-frags in regs, MFMA-pred side column
//    (wave w<4 preds row-tile w, W_out hi+lo frags from LDS), bias+x*Wih
//    folded into MFMA C-init, exp2-form fused-reciprocal cell math,
//    fp16 h via dbuf LDS, 1 barrier/t.

#define SEQ 7
#define BT 64

typedef _Float16 half8 __attribute__((ext_vector_type(8)));
typedef float floatx4 __attribute__((ext_vector_type(4)));

__device__ __forceinline__ floatx4 mfma16(half8 a, half8 b, floatx4 c) {
  return __builtin_amdgcn_mfma_f32_16x16x32_f16(a, b, c, 0, 0, 0);
}

#define LOG2E 1.4426950408889634f
#define K2 2.885390081777927f  // 2*log2e

// Pack W_hh [512][128] fp32 -> B-fragment-major fp16, prescaled (idx<65536):
//   Bp[((nt*4+kk)*64 + lane)*8 + jj] = S(g) * Whh[j][k]
//   nt=g*8+w, j=g*128+w*16+col, k=32kk+8quad+jj (B-layout: lane kq*16+col
//   holds B[k=kq*8+jj][n=col] -- R7-proven).
// idx in [65536, 69632): W_out hi/lo fragments, col-0-only 16-col tile.
__global__ void pack_kernel(const float* __restrict__ Whh,
                            const float* __restrict__ Wout,
                            _Float16* __restrict__ Bp) {
  int idx = blockIdx.x * 256 + threadIdx.x;  // 0..69631
  if (idx < 65536) {
    int jj = idx & 7;
    int lane = (idx >> 3) & 63;
    int kk = (idx >> 9) & 3;
    int nt = idx >> 11;  // 0..31
    int g = nt >> 3, w = nt & 7;
    int col = lane & 15, quad = lane >> 4;
    int j = g * 128 + w * 16 + col;
    int k = 32 * kk + 8 * quad + jj;
    float S = (g == 2) ? K2 : LOG2E;
    Bp[idx] = (_Float16)(S * Whh[j * 128 + k]);
  } else {
    int pos = idx - 65536;  // 0..4095
    int hl = pos >> 11;     // 0 = hi, 1 = lo
    int e = pos & 2047;
    int jj = e & 7;
    int lane = (e >> 3) & 63;
    int kk = e >> 9;
    int col = lane & 15, quad = lane >> 4;
    int k = 32 * kk + 8 * quad + jj;
    float wv = Wout[k];
    _Float16 hi = (_Float16)wv;
    _Float16 v = hl ? (_Float16)(wv - (float)hi) : hi;
    Bp[idx] = (col == 0) ? v : (_Float16)0.0f;
  }
}

__launch_bounds__(512, 2)
__global__ void lstm_kernel(const float* __restrict__ x,
                            const float* __restrict__ x0,
                            const float* __restrict__ Wih,
                            const float* __restrict__ bih,
                            const float* __restrict__ bhh,
                            const float* __restrict__ boutp,
                            const _Float16* __restrict__ Bp,
                            float* __restrict__ out) {
  // h staged fp16, double-buffered, 272B row stride (+8 pad).
  __shared__ _Float16 Ah[2][BT][136];  // 34,816 B
  __shared__ float xs[2][BT];          // 512 B
  __shared__ _Float16 Wo[4096];        // 8 KB W_out hi/lo B-fragments

  const int tid = threadIdx.x;
  const int w = tid >> 6;  // wave 0..7: owns hcols [16w, 16w+16)
  const int lane = tid & 63;
  const int col = lane & 15;
  const int quad = lane >> 4;
  const int rowbase = blockIdx.x * BT;

  // stage W_out fragments into LDS (512 x 16B)
  if (tid < 512) ((half8*)Wo)[tid] = ((const half8*)(Bp + 65536))[tid];

  // Gate-GEMM weight fragments: 64 VGPR, loaded once for all timesteps.
  half8 bw[4][4];
#pragma unroll
  for (int g = 0; g < 4; ++g)
#pragma unroll
    for (int kk = 0; kk < 4; ++kk)
      bw[g][kk] =
          *(const half8*)(Bp + (((g * 8 + w) * 4 + kk) * 64 + lane) * 8);

  // Per-lane epilogue constants, gate-col j = g*128 + 16w + col.
  float wih_r[4], bias_r[4];
#pragma unroll
  for (int g = 0; g < 4; ++g) {
    int j = g * 128 + w * 16 + col;
    float S = (g == 2) ? K2 : LOG2E;
    wih_r[g] = S * Wih[j];
    bias_r[g] = S * (bih[j] + bhh[j]);
  }
  const float bout = boutp[0];

  // Scaled cell state c~ = 2log2e*c, static-indexed -> registers.
  float c_r[4][4];
#pragma unroll
  for (int mt = 0; mt < 4; ++mt)
#pragma unroll
    for (int r = 0; r < 4; ++r) c_r[mt][r] = 0.f;

  if (tid < BT) xs[0][tid] = x0[rowbase + tid];  // t=0 consumes x0
  __syncthreads();

#pragma unroll 1
  for (int t = 0; t < SEQ; ++t) {
    const int cur = t & 1, nxt = cur ^ 1;

    // prefetch input for t+1 (consumes x[:, t])
    if (t + 1 < SEQ && tid < BT) {
      xs[nxt][tid] = x[(size_t)(rowbase + tid) * 7 + t];
    }

#pragma unroll
    for (int mt = 0; mt < 4; ++mt) {
      // x for the 4 rows (mt*16 + quad*4 + r) this lane covers.
      floatx4 xq = *(const floatx4*)&xs[cur][mt * 16 + quad * 4];

      // acc init = x*W_ih + bias (prescaled) -> MFMA C operand.
      floatx4 acc[4];
#pragma unroll
      for (int g = 0; g < 4; ++g)
#pragma unroll
        for (int r = 0; r < 4; ++r)
          acc[g][r] = __builtin_fmaf(wih_r[g], xq[r], bias_r[g]);

      const bool dopred = (w < 4) && (mt == w);  // wave-uniform

      if (t != 0) {  // h(0)=0: skip GEMM at t=0
        floatx4 ap = (floatx4){0.f, 0.f, 0.f, 0.f};  // pred(t-1) partial
#pragma unroll
        for (int kk = 0; kk < 4; ++kk) {
          half8 ah =
              *(const half8*)&Ah[cur][mt * 16 + col][kk * 32 + quad * 8];
#pragma unroll
          for (int g = 0; g < 4; ++g) acc[g] = mfma16(ah, bw[g][kk], acc[g]);
          if (dopred) {  // wave w preds its own row tile (full K in ah)
            half8 bo0 = *(const half8*)&Wo[(kk * 64 + lane) * 8];
            half8 bo1 = *(const half8*)&Wo[2048 + (kk * 64 + lane) * 8];
            ap = mfma16(ah, bo0, ap);
            ap = mfma16(ah, bo1, ap);
          }
        }
        if (dopred && col == 0) {
#pragma unroll
          for (int r = 0; r < 4; ++r)
            out[(size_t)(rowbase + mt * 16 + quad * 4 + r) * 7 + (t - 1)] =
                ap[r] + bout;
        }
      }

      // Fused-reciprocal cell update (exp2 form, prescaled weights):
      //   A=2^-Gi', B=2^-Gf', C=2^-Gg'', D=2^-Go'
      //   c~' = [c~(1+A)(1+C) + K2(1-C)(1+B)] / [(1+A)(1+B)(1+C)]
      //   E = 2^-c~' ; h = (1-E)/[(1+D)(1+E)]
#pragma unroll
      for (int r = 0; r < 4; ++r) {
        float A = __builtin_amdgcn_exp2f(-acc[0][r]);
        float Bv = __builtin_amdgcn_exp2f(-acc[1][r]);
        float Cv = __builtin_amdgcn_exp2f(-acc[2][r]);
        float Dv = __builtin_amdgcn_exp2f(-acc[3][r]);
        float a1 = 1.0f + A, b1 = 1.0f + Bv, c1 = 1.0f + Cv;
        float ac = a1 * c1;
        float t1 = __builtin_fmaf(Cv, -K2, K2);  // K2*(1-C)
        float num = __builtin_fmaf(c_r[mt][r], ac, t1 * b1);
        float cn = num * __builtin_amdgcn_rcpf(ac * b1);
        c_r[mt][r] = cn;
        float E = __builtin_amdgcn_exp2f(-cn);
        float hn =
            (1.0f - E) * __builtin_amdgcn_rcpf((1.0f + Dv) * (1.0f + E));
        // stage h_new (fp16); lane owns hcol 16w+col
        Ah[nxt][mt * 16 + quad * 4 + r][w * 16 + col] = (_Float16)hn;
      }
    }
    // single barrier per t: h staging + xs prefetch complete
    __syncthreads();
  }

  // tail: pred(6) from h(6) staged in Ah[1]
  if (w < 4) {
    const int mt = w;
    floatx4 ap = (floatx4){0.f, 0.f, 0.f, 0.f};
#pragma unroll
    for (int kk = 0; kk < 4; ++kk) {
      half8 ah = *(const half8*)&Ah[1][mt * 16 + col][kk * 32 + quad * 8];
      half8 bo0 = *(const half8*)&Wo[(kk * 64 + lane) * 8];
      half8 bo1 = *(const half8*)&Wo[2048 + (kk * 64 + lane) * 8];
      ap = mfma16(ah, bo0, ap);
      ap = mfma16(ah, bo1, ap);
    }
    if (col == 0) {
#pragma unroll
      for (int r = 0; r < 4; ++r)
        out[(size_t)(rowbase + mt * 16 + quad * 4 + r) * 7 + 6] =
            ap[r] + bout;
    }
  }
}

extern "C" void kernel_launch(void* const* d_in, const int* in_sizes, int n_in,
                              void* d_out, int out_size, void* d_ws,
                              size_t ws_size, hipStream_t stream) {
  const float* x = (const float*)d_in[0];
  const float* x0 = (const float*)d_in[1];
  const float* Wih = (const float*)d_in[2];
  const float* Whh = (const float*)d_in[3];
  const float* bih = (const float*)d_in[4];
  const float* bhh = (const float*)d_in[5];
  const float* Wout = (const float*)d_in[6];
  const float* bout = (const float*)d_in[7];
  float* out = (float*)d_out;
  _Float16* Bp = (_Float16*)d_ws;  // 136 KB packed weights + wout frags

  pack_kernel<<<272, 256, 0, stream>>>(Whh, Wout, Bp);
  lstm_kernel<<<65536 / BT, 512, 0, stream>>>(x, x0, Wih, bih, bhh, bout, Bp,
                                              out);
}

// Round 8
// 152.776 us; speedup vs baseline: 3.8843x; 1.0345x over previous
//
#include <hip/hip_runtime.h>

// LSTM: HIDDEN=128, SEQ=7, BATCH=65536. fp32 in/out.
//
// R15 (third attempt at the packed-f32 epilogue; rounds 6 & 7 died in the
// broker with the kernel unrun). Same semantics as R13/R14, maximally
// conservative syntax in case the toolchain choked:
//  * no pointer-reinterpret into ext-vector storage (element-wise pair
//    extraction instead),
//  * all packed math written vector (x) vector with explicit broadcast
//    constants, via tiny inline helpers.
// Base = R12-proven structure: weight-stationary AGPR B-frags, MFMA-pred
// side column, bias folded into MFMA C-init, exp2 fused-reciprocal cell
// math, fp16 h via dbuf LDS, 1 barrier/t, (512,2), BT=64.
//  * R12 post-mortem: VALU-issue-bound. 288 VALU/lane/t x 32 wave-blocks/CU
//    x 7t x 2cyc = 54us = measured VALUBusy (50% of 102us). MFMA 6us,
//    LDS 4us, ~35us barrier/latency idle.
//  * This round: float2 pairs (r01/r23) -> v_pk_{fma,mul,add}_f32 halve
//    non-trans VALU. Trans (5 exp2 + 2 rcp / element) stays scalar.

#define SEQ 7
#define BT 64

typedef _Float16 half8 __attribute__((ext_vector_type(8)));
typedef float floatx4 __attribute__((ext_vector_type(4)));
typedef float floatx2 __attribute__((ext_vector_type(2)));

__device__ __forceinline__ floatx4 mfma16(half8 a, half8 b, floatx4 c) {
  return __builtin_amdgcn_mfma_f32_16x16x32_f16(a, b, c, 0, 0, 0);
}

#define LOG2E 1.4426950408889634f
#define K2 2.885390081777927f  // 2*log2e

// packed helpers: exp2(-v) and rcp(v), scalar trans ops on both halves
__device__ __forceinline__ floatx2 pexp2m(floatx2 v) {
  floatx2 r;
  r.x = __builtin_amdgcn_exp2f(-v.x);
  r.y = __builtin_amdgcn_exp2f(-v.y);
  return r;
}
__device__ __forceinline__ floatx2 prcp(floatx2 v) {
  floatx2 r;
  r.x = __builtin_amdgcn_rcpf(v.x);
  r.y = __builtin_amdgcn_rcpf(v.y);
  return r;
}

// Pack W_hh [512][128] fp32 -> B-fragment-major fp16, prescaled (idx<65536):
//   Bp[((nt*4+kk)*64 + lane)*8 + jj] = S(g) * Whh[j][k]
//   nt=g*8+w, j=g*128+w*16+col, k=32kk+8quad+jj (B-layout: lane kq*16+col
//   holds B[k=kq*8+jj][n=col] -- R7-proven).
// idx in [65536, 69632): W_out hi/lo fragments, col-0-only 16-col tile.
__global__ void pack_kernel(const float* __restrict__ Whh,
                            const float* __restrict__ Wout,
                            _Float16* __restrict__ Bp) {
  int idx = blockIdx.x * 256 + threadIdx.x;  // 0..69631
  if (idx < 65536) {
    int jj = idx & 7;
    int lane = (idx >> 3) & 63;
    int kk = (idx >> 9) & 3;
    int nt = idx >> 11;  // 0..31
    int g = nt >> 3, w = nt & 7;
    int col = lane & 15, quad = lane >> 4;
    int j = g * 128 + w * 16 + col;
    int k = 32 * kk + 8 * quad + jj;
    float S = (g == 2) ? K2 : LOG2E;
    Bp[idx] = (_Float16)(S * Whh[j * 128 + k]);
  } else {
    int pos = idx - 65536;  // 0..4095
    int hl = pos >> 11;     // 0 = hi, 1 = lo
    int e = pos & 2047;
    int jj = e & 7;
    int lane = (e >> 3) & 63;
    int kk = e >> 9;
    int col = lane & 15, quad = lane >> 4;
    int k = 32 * kk + 8 * quad + jj;
    float wv = Wout[k];
    _Float16 hi = (_Float16)wv;
    _Float16 v = hl ? (_Float16)(wv - (float)hi) : hi;
    Bp[idx] = (col == 0) ? v : (_Float16)0.0f;
  }
}

__launch_bounds__(512, 2)
__global__ void lstm_kernel(const float* __restrict__ x,
                            const float* __restrict__ x0,
                            const float* __restrict__ Wih,
                            const float* __restrict__ bih,
                            const float* __restrict__ bhh,
                            const float* __restrict__ boutp,
                            const _Float16* __restrict__ Bp,
                            float* __restrict__ out) {
  // h staged fp16, double-buffered, 272B row stride (+8 pad).
  __shared__ _Float16 Ah[2][BT][136];  // 34,816 B
  __shared__ float xs[2][BT];          // 512 B
  __shared__ _Float16 Wo[4096];        // 8 KB W_out hi/lo B-fragments

  const int tid = threadIdx.x;
  const int w = tid >> 6;  // wave 0..7: owns hcols [16w, 16w+16)
  const int lane = tid & 63;
  const int col = lane & 15;
  const int quad = lane >> 4;
  const int rowbase = blockIdx.x * BT;

  // stage W_out fragments into LDS (512 x 16B)
  if (tid < 512) ((half8*)Wo)[tid] = ((const half8*)(Bp + 65536))[tid];

  // Gate-GEMM weight fragments: 64 regs (AGPR-resident), loaded once.
  half8 bw[4][4];
#pragma unroll
  for (int g = 0; g < 4; ++g)
#pragma unroll
    for (int kk = 0; kk < 4; ++kk)
      bw[g][kk] =
          *(const half8*)(Bp + (((g * 8 + w) * 4 + kk) * 64 + lane) * 8);

  // Per-lane epilogue constants, gate-col j = g*128 + 16w + col.
  float wih_r[4], bias_r[4];
#pragma unroll
  for (int g = 0; g < 4; ++g) {
    int j = g * 128 + w * 16 + col;
    float S = (g == 2) ? K2 : LOG2E;
    wih_r[g] = S * Wih[j];
    bias_r[g] = S * (bih[j] + bhh[j]);
  }
  const float bout = boutp[0];

  const floatx2 one2 = {1.0f, 1.0f};
  const floatx2 k22 = {K2, K2};

  // Scaled cell state c~ = 2log2e*c, pair-major float2 -> registers.
  floatx2 c2[4][2];
#pragma unroll
  for (int mt = 0; mt < 4; ++mt)
#pragma unroll
    for (int p = 0; p < 2; ++p) c2[mt][p] = (floatx2){0.f, 0.f};

  if (tid < BT) xs[0][tid] = x0[rowbase + tid];  // t=0 consumes x0
  __syncthreads();

#pragma unroll 1
  for (int t = 0; t < SEQ; ++t) {
    const int cur = t & 1, nxt = cur ^ 1;

    // prefetch input for t+1 (consumes x[:, t])
    if (t + 1 < SEQ && tid < BT) {
      xs[nxt][tid] = x[(size_t)(rowbase + tid) * 7 + t];
    }

#pragma unroll
    for (int mt = 0; mt < 4; ++mt) {
      // x for the 4 rows (mt*16 + quad*4 + r) this lane covers.
      floatx4 xq = *(const floatx4*)&xs[cur][mt * 16 + quad * 4];

      // acc init = x*W_ih + bias (prescaled) -> MFMA C operand.
      floatx4 acc[4];
#pragma unroll
      for (int g = 0; g < 4; ++g)
#pragma unroll
        for (int r = 0; r < 4; ++r)
          acc[g][r] = __builtin_fmaf(wih_r[g], xq[r], bias_r[g]);

      const bool dopred = (w < 4) && (mt == w);  // wave-uniform

      if (t != 0) {  // h(0)=0: skip GEMM at t=0
        floatx4 ap = (floatx4){0.f, 0.f, 0.f, 0.f};  // pred(t-1) partial
#pragma unroll
        for (int kk = 0; kk < 4; ++kk) {
          half8 ah =
              *(const half8*)&Ah[cur][mt * 16 + col][kk * 32 + quad * 8];
#pragma unroll
          for (int g = 0; g < 4; ++g) acc[g] = mfma16(ah, bw[g][kk], acc[g]);
          if (dopred) {  // wave w preds its own row tile (full K in ah)
            half8 bo0 = *(const half8*)&Wo[(kk * 64 + lane) * 8];
            half8 bo1 = *(const half8*)&Wo[2048 + (kk * 64 + lane) * 8];
            ap = mfma16(ah, bo0, ap);
            ap = mfma16(ah, bo1, ap);
          }
        }
        if (dopred && col == 0) {
#pragma unroll
          for (int r = 0; r < 4; ++r)
            out[(size_t)(rowbase + mt * 16 + quad * 4 + r) * 7 + (t - 1)] =
                ap[r] + bout;
        }
      }

      // Fused-reciprocal cell update, PACKED pairs (r01, r23):
      //   A=2^-Gi', B=2^-Gf', C=2^-Gg'', D=2^-Go'
      //   c~' = [c~(1+A)(1+C) + K2(1-C)(1+B)] / [(1+A)(1+B)(1+C)]
      //   E = 2^-c~' ; h = (1-E)/[(1+D)(1+E)]
#pragma unroll
      for (int p = 0; p < 2; ++p) {
        floatx2 Gi, Gf, Gg, Go;
        Gi.x = acc[0][2 * p];
        Gi.y = acc[0][2 * p + 1];
        Gf.x = acc[1][2 * p];
        Gf.y = acc[1][2 * p + 1];
        Gg.x = acc[2][2 * p];
        Gg.y = acc[2][2 * p + 1];
        Go.x = acc[3][2 * p];
        Go.y = acc[3][2 * p + 1];
        floatx2 A = pexp2m(Gi);
        floatx2 Bv = pexp2m(Gf);
        floatx2 Cv = pexp2m(Gg);
        floatx2 Dv = pexp2m(Go);
        floatx2 a1 = A + one2;
        floatx2 b1 = Bv + one2;
        floatx2 c1 = Cv + one2;
        floatx2 ac = a1 * c1;
        floatx2 t1 = k22 - Cv * k22;
        floatx2 num = c2[mt][p] * ac + t1 * b1;
        floatx2 den = ac * b1;
        floatx2 cn = num * prcp(den);
        c2[mt][p] = cn;
        floatx2 E = pexp2m(cn);
        floatx2 de = (Dv + one2) * (E + one2);
        floatx2 hn = (one2 - E) * prcp(de);
        // stage h_new (fp16); lane owns hcol 16w+col; rows 2p, 2p+1
        Ah[nxt][mt * 16 + quad * 4 + 2 * p][w * 16 + col] = (_Float16)hn.x;
        Ah[nxt][mt * 16 + quad * 4 + 2 * p + 1][w * 16 + col] =
            (_Float16)hn.y;
      }
    }
    // single barrier per t: h staging + xs prefetch complete
    __syncthreads();
  }

  // tail: pred(6) from h(6) staged in Ah[1]
  if (w < 4) {
    const int mt = w;
    floatx4 ap = (floatx4){0.f, 0.f, 0.f, 0.f};
#pragma unroll
    for (int kk = 0; kk < 4; ++kk) {
      half8 ah = *(const half8*)&Ah[1][mt * 16 + col][kk * 32 + quad * 8];
      half8 bo0 = *(const half8*)&Wo[(kk * 64 + lane) * 8];
      half8 bo1 = *(const half8*)&Wo[2048 + (kk * 64 + lane) * 8];
      ap = mfma16(ah, bo0, ap);
      ap = mfma16(ah, bo1, ap);
    }
    if (col == 0) {
#pragma unroll
      for (int r = 0; r < 4; ++r)
        out[(size_t)(rowbase + mt * 16 + quad * 4 + r) * 7 + 6] =
            ap[r] + bout;
    }
  }
}

extern "C" void kernel_launch(void* const* d_in, const int* in_sizes, int n_in,
                              void* d_out, int out_size, void* d_ws,
                              size_t ws_size, hipStream_t stream) {
  const float* x = (const float*)d_in[0];
  const float* x0 = (const float*)d_in[1];
  const float* Wih = (const float*)d_in[2];
  const float* Whh = (const float*)d_in[3];
  const float* bih = (const float*)d_in[4];
  const float* bhh = (const float*)d_in[5];
  const float* Wout = (const float*)d_in[6];
  const float* bout = (const float*)d_in[7];
  float* out = (float*)d_out;
  _Float16* Bp = (_Float16*)d_ws;  // 136 KB packed weights + wout frags

  pack_kernel<<<272, 256, 0, stream>>>(Whh, Wout, Bp);
  lstm_kernel<<<65536 / BT, 512, 0, stream>>>(x, x0, Wih, bih, bhh, bout, Bp,
                                              out);
}